// Round 1
// baseline (89.551 us; speedup 1.0000x reference)
//
#include <hip/hip_runtime.h>

// KroneckerGATorch: out = sum_p w_p * kron(B_{p,0},...,B_{p,7})  (256x256 fp32)
//
// Factorization: kron8 = A_p (codons 0..3, 16x16) ⊗ B_p (codons 4..7, 16x16)
//   out[(i1*16+i2)*256 + (j1*16+j2)] = sum_p (w_p*A_p[i1,j1]) * B_p[i2,j2]
// => GEMM over m=(i1,j1), n=(i2,j2), K=4096, with A/B entries generated on the
//    fly from the 36x2x2 building-block table (products of 4 entries).
//
// Grid: 4 m-tiles x 4 n-tiles x 16 K-chunks (256 blocks, 1 per CU).
// Block: 256 threads (16x16), each owning a 4x4 register tile of C.
// K-chunk = 256 genomes, staged in 4 sub-chunks of 64 into LDS.
// Epilogue: atomicAdd partials into zeroed d_out.

__global__ __launch_bounds__(256) void kron_ga_kernel(
    const float* __restrict__ weights,
    const int*   __restrict__ indices,
    const float* __restrict__ bb,
    float*       __restrict__ out)
{
    __shared__ float sA[64][64];   // sA[genome][m_local] = w * A entries
    __shared__ float sB[64][64];   // sB[genome][n_local] = B entries
    __shared__ float sbb[144];     // 36 blocks * 4 entries
    __shared__ float sw[64];
    __shared__ int   sidx[64 * 8];

    const int tid = threadIdx.x;
    const int tx  = tid & 15;      // n sub-tile (4 cols)
    const int ty  = tid >> 4;      // m sub-tile (4 rows)
    const int m0  = blockIdx.y * 64;
    const int n0  = blockIdx.x * 64;
    const int pbase = blockIdx.z * 256;

    if (tid < 144) sbb[tid] = bb[tid];

    // Staging role: this thread fills column `lane` of sA/sB for 16 genomes.
    const int lane  = tid & 63;          // m_local / n_local column
    const int gbase = (tid >> 6) * 16;   // which 16 genomes

    // Precompute per-codon (row,col) sub-offsets for this thread's m and n.
    const int m  = m0 + lane;
    const int i1 = m >> 4, j1 = m & 15;
    const int n  = n0 + lane;
    const int i2 = n >> 4, j2 = n & 15;
    int offA[4], offB[4];
#pragma unroll
    for (int c = 0; c < 4; ++c) {
        offA[c] = (((i1 >> (3 - c)) & 1) << 1) | ((j1 >> (3 - c)) & 1);
        offB[c] = (((i2 >> (3 - c)) & 1) << 1) | ((j2 >> (3 - c)) & 1);
    }

    float acc[4][4];
#pragma unroll
    for (int i = 0; i < 4; ++i)
#pragma unroll
        for (int j = 0; j < 4; ++j) acc[i][j] = 0.f;

    for (int sub = 0; sub < 4; ++sub) {
        const int p0 = pbase + sub * 64;
        __syncthreads();   // previous iteration's readers done (also covers sbb)
        if (tid < 64) sw[tid] = weights[p0 + tid];
        sidx[tid]       = indices[p0 * 8 + tid];         // 512 ints, coalesced
        sidx[tid + 256] = indices[p0 * 8 + 256 + tid];
        __syncthreads();

        // Stage sA (w * kron4 of codons 0..3) and sB (kron4 of codons 4..7).
        // Lanes write consecutive columns -> conflict-free; sbb/sidx/sw reads
        // are wave-uniform or <=4-address broadcasts.
#pragma unroll
        for (int gg = 0; gg < 16; ++gg) {
            const int g = gbase + gg;
            const int* gi = &sidx[g * 8];
            const float w = sw[g];
            const float a = sbb[gi[0] * 4 + offA[0]] * sbb[gi[1] * 4 + offA[1]]
                          * sbb[gi[2] * 4 + offA[2]] * sbb[gi[3] * 4 + offA[3]];
            sA[g][lane] = w * a;
            const float b = sbb[gi[4] * 4 + offB[0]] * sbb[gi[5] * 4 + offB[1]]
                          * sbb[gi[6] * 4 + offB[2]] * sbb[gi[7] * 4 + offB[3]];
            sB[g][lane] = b;
        }
        __syncthreads();

        // Main GEMM loop: 64 genomes, 4x4 register tile per thread.
#pragma unroll 4
        for (int kk = 0; kk < 64; ++kk) {
            const float4 av = *(const float4*)&sA[kk][ty * 4];
            const float4 bv = *(const float4*)&sB[kk][tx * 4];
            const float a4[4] = {av.x, av.y, av.z, av.w};
            const float b4[4] = {bv.x, bv.y, bv.z, bv.w};
#pragma unroll
            for (int i = 0; i < 4; ++i)
#pragma unroll
                for (int j = 0; j < 4; ++j)
                    acc[i][j] += a4[i] * b4[j];
        }
    }

    // Scatter-accumulate partial tile into the interleaved output layout.
#pragma unroll
    for (int i = 0; i < 4; ++i) {
        const int mm  = m0 + ty * 4 + i;
        const int ri1 = mm >> 4, rj1 = mm & 15;
#pragma unroll
        for (int j = 0; j < 4; ++j) {
            const int nn  = n0 + tx * 4 + j;
            const int ri2 = nn >> 4, rj2 = nn & 15;
            atomicAdd(&out[(ri1 * 16 + ri2) * 256 + (rj1 * 16 + rj2)], acc[i][j]);
        }
    }
}

extern "C" void kernel_launch(void* const* d_in, const int* in_sizes, int n_in,
                              void* d_out, int out_size, void* d_ws, size_t ws_size,
                              hipStream_t stream) {
    const float* weights = (const float*)d_in[0];   // [4096]
    const int*   indices = (const int*)d_in[1];     // [4096, 8]
    const float* bb      = (const float*)d_in[2];   // [36, 2, 2]
    float* out = (float*)d_out;                     // [256, 256]

    hipMemsetAsync(out, 0, (size_t)out_size * sizeof(float), stream);

    dim3 grid(4, 4, 16);   // n-tiles, m-tiles, K-chunks
    kron_ga_kernel<<<grid, 256, 0, stream>>>(weights, indices, bb, out);
}